// Round 6
// baseline (461.296 us; speedup 1.0000x reference)
//
#include <hip/hip_runtime.h>
#include <hip/hip_bf16.h>

// GraphSAGE 2-layer, bf16 MFMA version.
//   L1: h   = relu([agg1|x] @ [W1l;W1r] + b1)   K=256, N=256, bf16 MFMA
//   L2: [y2|t] = h @ [W2l|W2r] (+b2 on t)       K=256, N=80,  bf16 MFMA
//   out = mean_gather(y2) + t
// R6: gemm1+gemm2 fused (h lives in LDS only -> saves 102 MB round-trip +
//     1 dispatch); scan1/2/3 replaced by one decoupled-lookback scan;
//     prep+rank merged. 11 dispatches -> 7.

#define NN   100000
#define NNP  100096          // 782*128 = 1564*64
#define NE   800000
#define NB1  391             // ceil(NN/256)

typedef unsigned short ushortT;
typedef __attribute__((ext_vector_type(8))) short bf16x8;
typedef __attribute__((ext_vector_type(4))) float f32x4;

__device__ __forceinline__ unsigned short f2b(float f) {
    unsigned u = __float_as_uint(f);
    return (unsigned short)((u + 0x7fffu + ((u >> 16) & 1u)) >> 16);
}
__device__ __forceinline__ float b2f(unsigned short v) {
    return __uint_as_float(((unsigned)v) << 16);
}
__device__ __forceinline__ void llds16(const unsigned short* g, unsigned short* s) {
    __builtin_amdgcn_global_load_lds(
        (const __attribute__((address_space(1))) void*)g,
        (__attribute__((address_space(3))) void*)s, 16, 0, 0);
}

// ------------------------------------------------- prep + rank (one dispatch)
// blocks [0,12500): x->bf16 cast, weight transpose/cast, zero scan status
// blocks [12500,15625): rank[e] = old deg count (atomic)
__global__ __launch_bounds__(256) void k_prep_rank(
        const float* __restrict__ x,
        const float* __restrict__ W1l, const float* __restrict__ W1r,
        const float* __restrict__ W2l, const float* __restrict__ W2r,
        ushortT* __restrict__ Ac, ushortT* __restrict__ WT1,
        ushortT* __restrict__ WT2, int* __restrict__ stat,
        const int* __restrict__ dst, int* __restrict__ deg,
        int* __restrict__ rank) {
    int bid = blockIdx.x;
    if (bid < 12500) {
        int t = bid * 256 + threadIdx.x;          // [0, NN*32)
        int row = t >> 5, c4 = t & 31;
        float4 v = *(const float4*)&x[(size_t)row * 128 + c4 * 4];
        ushortT* p = Ac + (size_t)row * 256 + 128 + c4 * 4;
        p[0] = f2b(v.x); p[1] = f2b(v.y); p[2] = f2b(v.z); p[3] = f2b(v.w);

        if (t < 512) stat[t] = 0;
        if (t < 65536) {                          // WT1 [256n][256k]
            int n = t >> 8, k = t & 255;
            float w = (k < 128) ? W1l[(size_t)k * 256 + n]
                                : W1r[(size_t)(k - 128) * 256 + n];
            WT1[t] = f2b(w);
        } else if (t < 65536 + 20480) {           // WT2 [80n][256k]
            int j = t - 65536;
            int n = j >> 8, k = j & 255;
            float w = (n < 40) ? W2l[(size_t)k * 40 + n]
                               : W2r[(size_t)k * 40 + (n - 40)];
            WT2[j] = f2b(w);
        }
    } else {
        int e = (bid - 12500) * 256 + threadIdx.x;
        if (e < NE) rank[e] = atomicAdd(&deg[dst[e]], 1);
    }
}

// --------------------------------------- decoupled-lookback exclusive scan
__global__ __launch_bounds__(256) void k_scan(const int* __restrict__ deg,
                                              int* __restrict__ rp,
                                              int* __restrict__ aggv,
                                              int* __restrict__ prefv,
                                              int* __restrict__ stat) {
    __shared__ int s[256];
    __shared__ int sprefix;
    int t = threadIdx.x, b = blockIdx.x;
    int i = b * 256 + t;
    int v = (i < NN) ? deg[i] : 0;
    s[t] = v;
    __syncthreads();
    for (int off = 1; off < 256; off <<= 1) {
        int add = (t >= off) ? s[t - off] : 0;
        __syncthreads();
        s[t] += add;
        __syncthreads();
    }
    int total = s[255];
    if (t == 0) {
        if (b == 0) {
            __hip_atomic_store(&prefv[0], total, __ATOMIC_RELEASE, __HIP_MEMORY_SCOPE_AGENT);
            __hip_atomic_store(&stat[0], 2, __ATOMIC_RELEASE, __HIP_MEMORY_SCOPE_AGENT);
            sprefix = 0;
        } else {
            __hip_atomic_store(&aggv[b], total, __ATOMIC_RELEASE, __HIP_MEMORY_SCOPE_AGENT);
            __hip_atomic_store(&stat[b], 1, __ATOMIC_RELEASE, __HIP_MEMORY_SCOPE_AGENT);
            int run = 0, j = b - 1;
            while (true) {
                int sj;
                do {
                    sj = __hip_atomic_load(&stat[j], __ATOMIC_ACQUIRE, __HIP_MEMORY_SCOPE_AGENT);
                } while (sj == 0);
                if (sj == 2) {
                    run += __hip_atomic_load(&prefv[j], __ATOMIC_ACQUIRE, __HIP_MEMORY_SCOPE_AGENT);
                    break;
                }
                run += __hip_atomic_load(&aggv[j], __ATOMIC_ACQUIRE, __HIP_MEMORY_SCOPE_AGENT);
                --j;
            }
            __hip_atomic_store(&prefv[b], run + total, __ATOMIC_RELEASE, __HIP_MEMORY_SCOPE_AGENT);
            __hip_atomic_store(&stat[b], 2, __ATOMIC_RELEASE, __HIP_MEMORY_SCOPE_AGENT);
            sprefix = run;
        }
    }
    __syncthreads();
    if (i < NN) rp[i] = sprefix + s[t] - v;
    if (i == NN - 1) rp[NN] = NE;
}

// no atomic: position = rp[dst] + precomputed rank
__global__ __launch_bounds__(256) void k_fill(const int* __restrict__ src,
                                              const int* __restrict__ dst,
                                              const int* __restrict__ rank,
                                              const int* __restrict__ rp,
                                              int* __restrict__ col) {
    int e = blockIdx.x * 256 + threadIdx.x;
    if (e < NE) col[rp[dst[e]] + rank[e]] = src[e];
}

// ------------------------------------------------------- mean aggregation 1
// gather bf16 x rows (A_cat[:,128:]), write bf16 mean to A_cat[:,0:128].
// One wave per node; col prefetch + __shfl bcast; 8 row-loads in flight.
__global__ __launch_bounds__(256) void k_agg1(const int* __restrict__ rp,
                                              const int* __restrict__ col,
                                              ushortT* __restrict__ Ac) {
    int node = blockIdx.x * 4 + (threadIdx.x >> 6);
    int l = threadIdx.x & 63;
    if (node >= NN) return;
    int seg = l >> 4, dl = l & 15;
    int beg = rp[node];
    int deg = rp[node + 1] - beg;
    float a[8] = {0.f, 0.f, 0.f, 0.f, 0.f, 0.f, 0.f, 0.f};
    for (int base = 0; base < deg; base += 64) {
        int cnt = min(64, deg - base);
        int cv = col[beg + base + min(l, cnt - 1)];
        for (int j = 0; j < cnt; j += 8) {
            int e0 = j + seg, e1 = j + 4 + seg;
            int i0 = __shfl(cv, min(e0, cnt - 1));
            int i1 = __shfl(cv, min(e1, cnt - 1));
            bf16x8 v0 = {0, 0, 0, 0, 0, 0, 0, 0};
            bf16x8 v1 = {0, 0, 0, 0, 0, 0, 0, 0};
            if (e0 < cnt) v0 = *(const bf16x8*)(Ac + (size_t)i0 * 256 + 128 + dl * 8);
            if (e1 < cnt) v1 = *(const bf16x8*)(Ac + (size_t)i1 * 256 + 128 + dl * 8);
#pragma unroll
            for (int i = 0; i < 8; ++i)
                a[i] += b2f((unsigned short)v0[i]) + b2f((unsigned short)v1[i]);
        }
    }
#pragma unroll
    for (int i = 0; i < 8; ++i) {
        a[i] += __shfl_xor(a[i], 16);
        a[i] += __shfl_xor(a[i], 32);
    }
    if (seg == 0) {
        float inv = 1.0f / fmaxf((float)deg, 1.0f);
        bf16x8 o;
#pragma unroll
        for (int i = 0; i < 8; ++i) o[i] = (short)f2b(a[i] * inv);
        *(bf16x8*)(Ac + (size_t)node * 256 + dl * 8) = o;
    }
}

// --------------------------------------------------------- fused L1+L2 GEMM
// Per 64-row block:  phase1: h64x256 = relu(Ac @ WT1^T + b1) -> LDS only.
//                    phase2: [y2|t] = h @ WT2^T (+b2), B-frags from L2.
// 4 waves side-by-side in N (wave 64x64, acc 4x4 = 64 AGPR). LDS 41 KB.
#define HSP 264   // h-tile LDS row stride (+8 pad: 528B = 4-bank rotate/row)
__global__ __launch_bounds__(256, 3) void k_fused(
        const ushortT* __restrict__ Ac, const ushortT* __restrict__ WT1,
        const float* __restrict__ b1, const ushortT* __restrict__ WT2,
        const float* __restrict__ b2, ushortT* __restrict__ y2,
        float* __restrict__ t) {
    __shared__ ushortT As[64 * 64];      // 8 KB
    __shared__ ushortT Bs[64 * HSP];     // 33 KB; phase1 B uses [0,16384)
    const int tid = threadIdx.x, l = tid & 63, wid = tid >> 6;
    const int m0 = blockIdx.x * 64;
    const int q = l >> 4, r = l & 15;
    const int swz = (l & 7) ^ ((l >> 3) & 7);

    f32x4 acc[4][4];
#pragma unroll
    for (int i = 0; i < 4; ++i)
#pragma unroll
        for (int j = 0; j < 4; ++j) acc[i][j] = (f32x4){0.f, 0.f, 0.f, 0.f};

    for (int kt = 0; kt < 256; kt += 64) {
#pragma unroll
        for (int i = 0; i < 2; ++i) {             // A: 8 issues of 1 KB
            int flat = wid * 2 + i;
            int row = flat * 8 + (l >> 3);
            llds16(Ac + (size_t)(m0 + row) * 256 + kt + swz * 8, &As[flat * 512]);
        }
#pragma unroll
        for (int i = 0; i < 8; ++i) {             // B: 32 issues of 1 KB
            int flat = wid * 8 + i;
            int row = flat * 8 + (l >> 3);
            llds16(WT1 + (size_t)row * 256 + kt + swz * 8, &Bs[flat * 512]);
        }
        __syncthreads();
#pragma unroll
        for (int ks = 0; ks < 64; ks += 32) {
            bf16x8 af[4], bfr[4];
            const int cs = (((ks >> 3) + q) ^ (r & 7)) * 8;
#pragma unroll
            for (int mt = 0; mt < 4; ++mt)
                af[mt] = *(const bf16x8*)&As[(mt * 16 + r) * 64 + cs];
#pragma unroll
            for (int nt = 0; nt < 4; ++nt)
                bfr[nt] = *(const bf16x8*)&Bs[(wid * 64 + nt * 16 + r) * 64 + cs];
#pragma unroll
            for (int mt = 0; mt < 4; ++mt)
#pragma unroll
                for (int nt = 0; nt < 4; ++nt)
                    acc[mt][nt] = __builtin_amdgcn_mfma_f32_16x16x32_bf16(
                        af[mt], bfr[nt], acc[mt][nt], 0, 0, 0);
        }
        __syncthreads();
    }
    // phase-1 epilogue: +b1, relu, park h-tile in LDS (overwrite Bs)
#pragma unroll
    for (int nt = 0; nt < 4; ++nt) {
        int colb = wid * 64 + nt * 16 + r;
        float bb = b1[colb];
#pragma unroll
        for (int mt = 0; mt < 4; ++mt) {
            int rowb = mt * 16 + q * 4;
#pragma unroll
            for (int j = 0; j < 4; ++j)
                Bs[(rowb + j) * HSP + colb] = f2b(fmaxf(acc[mt][nt][j] + bb, 0.f));
        }
    }
    __syncthreads();

    // phase 2: [y2|t](64x80) = h(LDS) @ WT2^T; wave wid covers col-tiles
    // {wid, wid+4 if <5}; A-frags from LDS, B-frags straight from L2.
    f32x4 acc2[2][4];
#pragma unroll
    for (int i = 0; i < 2; ++i)
#pragma unroll
        for (int j = 0; j < 4; ++j) acc2[i][j] = (f32x4){0.f, 0.f, 0.f, 0.f};
#pragma unroll
    for (int kk = 0; kk < 256; kk += 32) {
        bf16x8 af[4];
#pragma unroll
        for (int mt = 0; mt < 4; ++mt)
            af[mt] = *(const bf16x8*)&Bs[(mt * 16 + r) * HSP + kk + q * 8];
#pragma unroll
        for (int cc = 0; cc < 2; ++cc) {
            int ct = wid + cc * 4;
            if (ct < 5) {
                bf16x8 bq = *(const bf16x8*)(WT2 + (size_t)(ct * 16 + r) * 256 + kk + q * 8);
#pragma unroll
                for (int mt = 0; mt < 4; ++mt)
                    acc2[cc][mt] = __builtin_amdgcn_mfma_f32_16x16x32_bf16(
                        af[mt], bq, acc2[cc][mt], 0, 0, 0);
            }
        }
    }
#pragma unroll
    for (int cc = 0; cc < 2; ++cc) {
        int ct = wid + cc * 4;
        if (ct >= 5) continue;
        int c = ct * 16 + r;
        float bb = (c >= 40) ? b2[c - 40] : 0.f;
#pragma unroll
        for (int mt = 0; mt < 4; ++mt) {
            int row0 = m0 + mt * 16 + q * 4;
#pragma unroll
            for (int j = 0; j < 4; ++j) {
                float v = acc2[cc][mt][j];
                if (c < 40)
                    y2[(size_t)(row0 + j) * 40 + c] = f2b(v);
                else
                    t[(size_t)(row0 + j) * 40 + (c - 40)] = v + bb;
            }
        }
    }
}

// ------------------------------------------------------- mean aggregation 2
// out = mean_gather(y2 bf16) + t; col prefetch + 8 loads in flight.
__global__ __launch_bounds__(256) void k_agg2(const int* __restrict__ rp,
                                              const int* __restrict__ col,
                                              const ushortT* __restrict__ y2,
                                              const float* __restrict__ t,
                                              float* __restrict__ out) {
    int node = blockIdx.x * 4 + (threadIdx.x >> 6);
    int l = threadIdx.x & 63;
    if (node >= NN) return;
    int seg = l >> 4, dl = l & 15;
    int beg = rp[node];
    int deg = rp[node + 1] - beg;
    bool act = dl < 10;
    float a0 = 0.f, a1 = 0.f, a2 = 0.f, a3 = 0.f;
    for (int base = 0; base < deg; base += 64) {
        int cnt = min(64, deg - base);
        int cv = col[beg + base + min(l, cnt - 1)];
        for (int j = 0; j < cnt; j += 8) {
            int e0 = j + seg, e1 = j + 4 + seg;
            int i0 = __shfl(cv, min(e0, cnt - 1));
            int i1 = __shfl(cv, min(e1, cnt - 1));
            ushort4 v0 = {0, 0, 0, 0}, v1 = {0, 0, 0, 0};
            if (e0 < cnt && act) v0 = *(const ushort4*)(y2 + (size_t)i0 * 40 + dl * 4);
            if (e1 < cnt && act) v1 = *(const ushort4*)(y2 + (size_t)i1 * 40 + dl * 4);
            a0 += b2f(v0.x) + b2f(v1.x);
            a1 += b2f(v0.y) + b2f(v1.y);
            a2 += b2f(v0.z) + b2f(v1.z);
            a3 += b2f(v0.w) + b2f(v1.w);
        }
    }
    a0 += __shfl_xor(a0, 16); a0 += __shfl_xor(a0, 32);
    a1 += __shfl_xor(a1, 16); a1 += __shfl_xor(a1, 32);
    a2 += __shfl_xor(a2, 16); a2 += __shfl_xor(a2, 32);
    a3 += __shfl_xor(a3, 16); a3 += __shfl_xor(a3, 32);
    if (seg == 0 && act) {
        float inv = 1.0f / fmaxf((float)deg, 1.0f);
        size_t o = (size_t)node * 40 + dl * 4;
        float4 tv = *(const float4*)&t[o];
        float4 ov;
        ov.x = a0 * inv + tv.x;
        ov.y = a1 * inv + tv.y;
        ov.z = a2 * inv + tv.z;
        ov.w = a3 * inv + tv.w;
        *(float4*)&out[o] = ov;
    }
}

// ------------------------------------------------------------------- launch
extern "C" void kernel_launch(void* const* d_in, const int* in_sizes, int n_in,
                              void* d_out, int out_size, void* d_ws, size_t ws_size,
                              hipStream_t stream) {
    const float* x   = (const float*)d_in[0];
    const int*   ei  = (const int*)d_in[1];
    const int*   src = ei;
    const int*   dst = ei + NE;
    const float* W1l = (const float*)d_in[2];
    const float* b1  = (const float*)d_in[3];
    const float* W1r = (const float*)d_in[4];
    const float* W2l = (const float*)d_in[5];
    const float* b2  = (const float*)d_in[6];
    const float* W2r = (const float*)d_in[7];
    float* out = (float*)d_out;

    size_t off = 0;
    char* base = (char*)d_ws;
    auto alloc = [&](size_t bytes) -> void* {
        void* p = base + off;
        off += (bytes + 255) & ~(size_t)255;
        return p;
    };
    int*     deg   = (int*)alloc((size_t)NN * 4);
    int*     rp    = (int*)alloc((size_t)(NN + 1) * 4);
    int*     rank  = (int*)alloc((size_t)NE * 4);
    int*     col   = (int*)alloc((size_t)NE * 4);
    int*     aggv  = (int*)alloc(512 * 4);
    int*     prefv = (int*)alloc(512 * 4);
    int*     stat  = (int*)alloc(512 * 4);
    ushortT* Ac    = (ushortT*)alloc((size_t)NNP * 256 * 2);   // [agg|x] bf16
    ushortT* y2    = (ushortT*)alloc((size_t)NNP * 40 * 2);
    float*   t     = (float*)alloc((size_t)NNP * 40 * 4);
    ushortT* WT1   = (ushortT*)alloc(256 * 256 * 2);
    ushortT* WT2   = (ushortT*)alloc(80 * 256 * 2);

    hipMemsetAsync(deg, 0, (size_t)NN * 4, stream);
    k_prep_rank<<<15625, 256, 0, stream>>>(x, W1l, W1r, W2l, W2r, Ac, WT1, WT2,
                                           stat, dst, deg, rank);
    k_scan<<<NB1, 256, 0, stream>>>(deg, rp, aggv, prefv, stat);
    k_fill<<<(NE + 255) / 256, 256, 0, stream>>>(src, dst, rank, rp, col);
    k_agg1<<<(NN + 3) / 4, 256, 0, stream>>>(rp, col, Ac);
    k_fused<<<NNP / 64, 256, 0, stream>>>(Ac, WT1, b1, WT2, b2, y2, t);
    k_agg2<<<(NN + 3) / 4, 256, 0, stream>>>(rp, col, y2, t, out);
}

// Round 7
// 276.595 us; speedup vs baseline: 1.6678x; 1.6678x over previous
//
#include <hip/hip_runtime.h>
#include <hip/hip_bf16.h>

// GraphSAGE 2-layer, bf16 MFMA version.
//   L1: h   = relu([agg1|x] @ [W1l;W1r] + b1)   K=256, N=256, bf16 MFMA
//   L2: [y2|t] = h @ [W2l|W2r] (+b2 on t)       K=256, N=80,  bf16 MFMA
//   out = mean_gather(y2) + t
// R7: revert decoupled-lookback scan (207 us! cross-XCD atomic polling) to
//     the 3-kernel hierarchical scan. Keep R6's fused GEMM (h in LDS only)
//     and merged prep+rank.

#define NN   100000
#define NNP  100096          // 782*128 = 1564*64
#define NE   800000
#define NB1  391             // ceil(NN/256)

typedef unsigned short ushortT;
typedef __attribute__((ext_vector_type(8))) short bf16x8;
typedef __attribute__((ext_vector_type(4))) float f32x4;

__device__ __forceinline__ unsigned short f2b(float f) {
    unsigned u = __float_as_uint(f);
    return (unsigned short)((u + 0x7fffu + ((u >> 16) & 1u)) >> 16);
}
__device__ __forceinline__ float b2f(unsigned short v) {
    return __uint_as_float(((unsigned)v) << 16);
}
__device__ __forceinline__ void llds16(const unsigned short* g, unsigned short* s) {
    __builtin_amdgcn_global_load_lds(
        (const __attribute__((address_space(1))) void*)g,
        (__attribute__((address_space(3))) void*)s, 16, 0, 0);
}

// ------------------------------------------------- prep + rank (one dispatch)
// blocks [0,12500): x->bf16 cast, weight transpose/cast
// blocks [12500,15625): rank[e] = old deg count (atomic)
__global__ __launch_bounds__(256) void k_prep_rank(
        const float* __restrict__ x,
        const float* __restrict__ W1l, const float* __restrict__ W1r,
        const float* __restrict__ W2l, const float* __restrict__ W2r,
        ushortT* __restrict__ Ac, ushortT* __restrict__ WT1,
        ushortT* __restrict__ WT2,
        const int* __restrict__ dst, int* __restrict__ deg,
        int* __restrict__ rank) {
    int bid = blockIdx.x;
    if (bid < 12500) {
        int t = bid * 256 + threadIdx.x;          // [0, NN*32)
        int row = t >> 5, c4 = t & 31;
        float4 v = *(const float4*)&x[(size_t)row * 128 + c4 * 4];
        ushortT* p = Ac + (size_t)row * 256 + 128 + c4 * 4;
        p[0] = f2b(v.x); p[1] = f2b(v.y); p[2] = f2b(v.z); p[3] = f2b(v.w);

        if (t < 65536) {                          // WT1 [256n][256k]
            int n = t >> 8, k = t & 255;
            float w = (k < 128) ? W1l[(size_t)k * 256 + n]
                                : W1r[(size_t)(k - 128) * 256 + n];
            WT1[t] = f2b(w);
        } else if (t < 65536 + 20480) {           // WT2 [80n][256k]
            int j = t - 65536;
            int n = j >> 8, k = j & 255;
            float w = (n < 40) ? W2l[(size_t)k * 40 + n]
                               : W2r[(size_t)k * 40 + (n - 40)];
            WT2[j] = f2b(w);
        }
    } else {
        int e = (bid - 12500) * 256 + threadIdx.x;
        if (e < NE) rank[e] = atomicAdd(&deg[dst[e]], 1);
    }
}

// ------------------------------------------------ hierarchical 3-phase scan
__global__ __launch_bounds__(256) void k_scan1(const int* __restrict__ deg,
                                               int* __restrict__ rp,
                                               int* __restrict__ bsum) {
    __shared__ int s[256];
    int t = threadIdx.x;
    int i = blockIdx.x * 256 + t;
    int v = (i < NN) ? deg[i] : 0;
    s[t] = v;
    __syncthreads();
    for (int off = 1; off < 256; off <<= 1) {
        int add = (t >= off) ? s[t - off] : 0;
        __syncthreads();
        s[t] += add;
        __syncthreads();
    }
    if (i < NN) rp[i] = s[t] - v;
    if (t == 255) bsum[blockIdx.x] = s[255];
}

__global__ __launch_bounds__(512) void k_scan2(int* __restrict__ bsum) {
    __shared__ int s[512];
    int t = threadIdx.x;
    int v = (t < NB1) ? bsum[t] : 0;
    s[t] = v;
    __syncthreads();
    for (int off = 1; off < 512; off <<= 1) {
        int add = (t >= off) ? s[t - off] : 0;
        __syncthreads();
        s[t] += add;
        __syncthreads();
    }
    if (t < NB1) bsum[t] = s[t] - v;
}

__global__ __launch_bounds__(256) void k_scan3(int* __restrict__ rp,
                                               const int* __restrict__ bsum) {
    int i = blockIdx.x * 256 + threadIdx.x;
    if (i < NN) rp[i] += bsum[blockIdx.x];
    if (i == 0) rp[NN] = NE;
}

// no atomic: position = rp[dst] + precomputed rank
__global__ __launch_bounds__(256) void k_fill(const int* __restrict__ src,
                                              const int* __restrict__ dst,
                                              const int* __restrict__ rank,
                                              const int* __restrict__ rp,
                                              int* __restrict__ col) {
    int e = blockIdx.x * 256 + threadIdx.x;
    if (e < NE) col[rp[dst[e]] + rank[e]] = src[e];
}

// ------------------------------------------------------- mean aggregation 1
// gather bf16 x rows (A_cat[:,128:]), write bf16 mean to A_cat[:,0:128].
// One wave per node; col prefetch + __shfl bcast; 8 row-loads in flight.
__global__ __launch_bounds__(256) void k_agg1(const int* __restrict__ rp,
                                              const int* __restrict__ col,
                                              ushortT* __restrict__ Ac) {
    int node = blockIdx.x * 4 + (threadIdx.x >> 6);
    int l = threadIdx.x & 63;
    if (node >= NN) return;
    int seg = l >> 4, dl = l & 15;
    int beg = rp[node];
    int deg = rp[node + 1] - beg;
    float a[8] = {0.f, 0.f, 0.f, 0.f, 0.f, 0.f, 0.f, 0.f};
    for (int base = 0; base < deg; base += 64) {
        int cnt = min(64, deg - base);
        int cv = col[beg + base + min(l, cnt - 1)];
        for (int j = 0; j < cnt; j += 8) {
            int e0 = j + seg, e1 = j + 4 + seg;
            int i0 = __shfl(cv, min(e0, cnt - 1));
            int i1 = __shfl(cv, min(e1, cnt - 1));
            bf16x8 v0 = {0, 0, 0, 0, 0, 0, 0, 0};
            bf16x8 v1 = {0, 0, 0, 0, 0, 0, 0, 0};
            if (e0 < cnt) v0 = *(const bf16x8*)(Ac + (size_t)i0 * 256 + 128 + dl * 8);
            if (e1 < cnt) v1 = *(const bf16x8*)(Ac + (size_t)i1 * 256 + 128 + dl * 8);
#pragma unroll
            for (int i = 0; i < 8; ++i)
                a[i] += b2f((unsigned short)v0[i]) + b2f((unsigned short)v1[i]);
        }
    }
#pragma unroll
    for (int i = 0; i < 8; ++i) {
        a[i] += __shfl_xor(a[i], 16);
        a[i] += __shfl_xor(a[i], 32);
    }
    if (seg == 0) {
        float inv = 1.0f / fmaxf((float)deg, 1.0f);
        bf16x8 o;
#pragma unroll
        for (int i = 0; i < 8; ++i) o[i] = (short)f2b(a[i] * inv);
        *(bf16x8*)(Ac + (size_t)node * 256 + dl * 8) = o;
    }
}

// --------------------------------------------------------- fused L1+L2 GEMM
// Per 64-row block:  phase1: h64x256 = relu(Ac @ WT1^T + b1) -> LDS only.
//                    phase2: [y2|t] = h @ WT2^T (+b2), B-frags from L2.
// 4 waves side-by-side in N (wave 64x64, acc 4x4 = 64 AGPR). LDS 41 KB.
#define HSP 264   // h-tile LDS row stride (+8 pad)
__global__ __launch_bounds__(256, 3) void k_fused(
        const ushortT* __restrict__ Ac, const ushortT* __restrict__ WT1,
        const float* __restrict__ b1, const ushortT* __restrict__ WT2,
        const float* __restrict__ b2, ushortT* __restrict__ y2,
        float* __restrict__ t) {
    __shared__ ushortT As[64 * 64];      // 8 KB
    __shared__ ushortT Bs[64 * HSP];     // 33 KB; phase1 B uses [0,16384)
    const int tid = threadIdx.x, l = tid & 63, wid = tid >> 6;
    const int m0 = blockIdx.x * 64;
    const int q = l >> 4, r = l & 15;
    const int swz = (l & 7) ^ ((l >> 3) & 7);

    f32x4 acc[4][4];
#pragma unroll
    for (int i = 0; i < 4; ++i)
#pragma unroll
        for (int j = 0; j < 4; ++j) acc[i][j] = (f32x4){0.f, 0.f, 0.f, 0.f};

    for (int kt = 0; kt < 256; kt += 64) {
#pragma unroll
        for (int i = 0; i < 2; ++i) {             // A: 8 issues of 1 KB
            int flat = wid * 2 + i;
            int row = flat * 8 + (l >> 3);
            llds16(Ac + (size_t)(m0 + row) * 256 + kt + swz * 8, &As[flat * 512]);
        }
#pragma unroll
        for (int i = 0; i < 8; ++i) {             // B: 32 issues of 1 KB
            int flat = wid * 8 + i;
            int row = flat * 8 + (l >> 3);
            llds16(WT1 + (size_t)row * 256 + kt + swz * 8, &Bs[flat * 512]);
        }
        __syncthreads();
#pragma unroll
        for (int ks = 0; ks < 64; ks += 32) {
            bf16x8 af[4], bfr[4];
            const int cs = (((ks >> 3) + q) ^ (r & 7)) * 8;
#pragma unroll
            for (int mt = 0; mt < 4; ++mt)
                af[mt] = *(const bf16x8*)&As[(mt * 16 + r) * 64 + cs];
#pragma unroll
            for (int nt = 0; nt < 4; ++nt)
                bfr[nt] = *(const bf16x8*)&Bs[(wid * 64 + nt * 16 + r) * 64 + cs];
#pragma unroll
            for (int mt = 0; mt < 4; ++mt)
#pragma unroll
                for (int nt = 0; nt < 4; ++nt)
                    acc[mt][nt] = __builtin_amdgcn_mfma_f32_16x16x32_bf16(
                        af[mt], bfr[nt], acc[mt][nt], 0, 0, 0);
        }
        __syncthreads();
    }
    // phase-1 epilogue: +b1, relu, park h-tile in LDS (overwrite Bs)
#pragma unroll
    for (int nt = 0; nt < 4; ++nt) {
        int colb = wid * 64 + nt * 16 + r;
        float bb = b1[colb];
#pragma unroll
        for (int mt = 0; mt < 4; ++mt) {
            int rowb = mt * 16 + q * 4;
#pragma unroll
            for (int j = 0; j < 4; ++j)
                Bs[(rowb + j) * HSP + colb] = f2b(fmaxf(acc[mt][nt][j] + bb, 0.f));
        }
    }
    __syncthreads();

    // phase 2: [y2|t](64x80) = h(LDS) @ WT2^T; wave wid covers col-tiles
    // {wid, wid+4 if <5}; A-frags from LDS, B-frags straight from L2.
    f32x4 acc2[2][4];
#pragma unroll
    for (int i = 0; i < 2; ++i)
#pragma unroll
        for (int j = 0; j < 4; ++j) acc2[i][j] = (f32x4){0.f, 0.f, 0.f, 0.f};
#pragma unroll
    for (int kk = 0; kk < 256; kk += 32) {
        bf16x8 af[4];
#pragma unroll
        for (int mt = 0; mt < 4; ++mt)
            af[mt] = *(const bf16x8*)&Bs[(mt * 16 + r) * HSP + kk + q * 8];
#pragma unroll
        for (int cc = 0; cc < 2; ++cc) {
            int ct = wid + cc * 4;
            if (ct < 5) {
                bf16x8 bq = *(const bf16x8*)(WT2 + (size_t)(ct * 16 + r) * 256 + kk + q * 8);
#pragma unroll
                for (int mt = 0; mt < 4; ++mt)
                    acc2[cc][mt] = __builtin_amdgcn_mfma_f32_16x16x32_bf16(
                        af[mt], bq, acc2[cc][mt], 0, 0, 0);
            }
        }
    }
#pragma unroll
    for (int cc = 0; cc < 2; ++cc) {
        int ct = wid + cc * 4;
        if (ct >= 5) continue;
        int c = ct * 16 + r;
        float bb = (c >= 40) ? b2[c - 40] : 0.f;
#pragma unroll
        for (int mt = 0; mt < 4; ++mt) {
            int row0 = m0 + mt * 16 + q * 4;
#pragma unroll
            for (int j = 0; j < 4; ++j) {
                float v = acc2[cc][mt][j];
                if (c < 40)
                    y2[(size_t)(row0 + j) * 40 + c] = f2b(v);
                else
                    t[(size_t)(row0 + j) * 40 + (c - 40)] = v + bb;
            }
        }
    }
}

// ------------------------------------------------------- mean aggregation 2
// out = mean_gather(y2 bf16) + t; col prefetch + 8 loads in flight.
__global__ __launch_bounds__(256) void k_agg2(const int* __restrict__ rp,
                                              const int* __restrict__ col,
                                              const ushortT* __restrict__ y2,
                                              const float* __restrict__ t,
                                              float* __restrict__ out) {
    int node = blockIdx.x * 4 + (threadIdx.x >> 6);
    int l = threadIdx.x & 63;
    if (node >= NN) return;
    int seg = l >> 4, dl = l & 15;
    int beg = rp[node];
    int deg = rp[node + 1] - beg;
    bool act = dl < 10;
    float a0 = 0.f, a1 = 0.f, a2 = 0.f, a3 = 0.f;
    for (int base = 0; base < deg; base += 64) {
        int cnt = min(64, deg - base);
        int cv = col[beg + base + min(l, cnt - 1)];
        for (int j = 0; j < cnt; j += 8) {
            int e0 = j + seg, e1 = j + 4 + seg;
            int i0 = __shfl(cv, min(e0, cnt - 1));
            int i1 = __shfl(cv, min(e1, cnt - 1));
            ushort4 v0 = {0, 0, 0, 0}, v1 = {0, 0, 0, 0};
            if (e0 < cnt && act) v0 = *(const ushort4*)(y2 + (size_t)i0 * 40 + dl * 4);
            if (e1 < cnt && act) v1 = *(const ushort4*)(y2 + (size_t)i1 * 40 + dl * 4);
            a0 += b2f(v0.x) + b2f(v1.x);
            a1 += b2f(v0.y) + b2f(v1.y);
            a2 += b2f(v0.z) + b2f(v1.z);
            a3 += b2f(v0.w) + b2f(v1.w);
        }
    }
    a0 += __shfl_xor(a0, 16); a0 += __shfl_xor(a0, 32);
    a1 += __shfl_xor(a1, 16); a1 += __shfl_xor(a1, 32);
    a2 += __shfl_xor(a2, 16); a2 += __shfl_xor(a2, 32);
    a3 += __shfl_xor(a3, 16); a3 += __shfl_xor(a3, 32);
    if (seg == 0 && act) {
        float inv = 1.0f / fmaxf((float)deg, 1.0f);
        size_t o = (size_t)node * 40 + dl * 4;
        float4 tv = *(const float4*)&t[o];
        float4 ov;
        ov.x = a0 * inv + tv.x;
        ov.y = a1 * inv + tv.y;
        ov.z = a2 * inv + tv.z;
        ov.w = a3 * inv + tv.w;
        *(float4*)&out[o] = ov;
    }
}

// ------------------------------------------------------------------- launch
extern "C" void kernel_launch(void* const* d_in, const int* in_sizes, int n_in,
                              void* d_out, int out_size, void* d_ws, size_t ws_size,
                              hipStream_t stream) {
    const float* x   = (const float*)d_in[0];
    const int*   ei  = (const int*)d_in[1];
    const int*   src = ei;
    const int*   dst = ei + NE;
    const float* W1l = (const float*)d_in[2];
    const float* b1  = (const float*)d_in[3];
    const float* W1r = (const float*)d_in[4];
    const float* W2l = (const float*)d_in[5];
    const float* b2  = (const float*)d_in[6];
    const float* W2r = (const float*)d_in[7];
    float* out = (float*)d_out;

    size_t off = 0;
    char* base = (char*)d_ws;
    auto alloc = [&](size_t bytes) -> void* {
        void* p = base + off;
        off += (bytes + 255) & ~(size_t)255;
        return p;
    };
    int*     deg   = (int*)alloc((size_t)NN * 4);
    int*     rp    = (int*)alloc((size_t)(NN + 1) * 4);
    int*     rank  = (int*)alloc((size_t)NE * 4);
    int*     col   = (int*)alloc((size_t)NE * 4);
    int*     bsum  = (int*)alloc(512 * 4);
    ushortT* Ac    = (ushortT*)alloc((size_t)NNP * 256 * 2);   // [agg|x] bf16
    ushortT* y2    = (ushortT*)alloc((size_t)NNP * 40 * 2);
    float*   t     = (float*)alloc((size_t)NNP * 40 * 4);
    ushortT* WT1   = (ushortT*)alloc(256 * 256 * 2);
    ushortT* WT2   = (ushortT*)alloc(80 * 256 * 2);

    hipMemsetAsync(deg, 0, (size_t)NN * 4, stream);
    k_prep_rank<<<15625, 256, 0, stream>>>(x, W1l, W1r, W2l, W2r, Ac, WT1, WT2,
                                           dst, deg, rank);
    k_scan1<<<NB1, 256, 0, stream>>>(deg, rp, bsum);
    k_scan2<<<1, 512, 0, stream>>>(bsum);
    k_scan3<<<NB1, 256, 0, stream>>>(rp, bsum);
    k_fill<<<(NE + 255) / 256, 256, 0, stream>>>(src, dst, rank, rp, col);
    k_agg1<<<(NN + 3) / 4, 256, 0, stream>>>(rp, col, Ac);
    k_fused<<<NNP / 64, 256, 0, stream>>>(Ac, WT1, b1, WT2, b2, y2, t);
    k_agg2<<<(NN + 3) / 4, 256, 0, stream>>>(rp, col, y2, t, out);
}

// Round 8
// 271.713 us; speedup vs baseline: 1.6977x; 1.0180x over previous
//
#include <hip/hip_runtime.h>
#include <hip/hip_bf16.h>

// GraphSAGE 2-layer, bf16 MFMA version.
//   L1: h   = relu([agg1|x] @ [W1l;W1r] + b1)   K=256, N=256, bf16 MFMA
//   L2: [y2|t] = h @ [W2l|W2r] (+b2 on t)       K=256, N=80,  bf16 MFMA
//   out = mean_gather(y2) + t
// R8: XCD-local deg replicas (deg8[r]) kill cross-XCD atomic line bouncing;
//     fill partitioned by dst-range so each col slice is written by one XCD;
//     scan3 removed (consumers add bsum on the fly); t stored bf16.

#define NN   100000
#define NNP  100096          // 782*128 = 1564*64
#define NE   800000
#define NB1  391             // ceil(NN/256)

typedef unsigned short ushortT;
typedef __attribute__((ext_vector_type(8))) short bf16x8;
typedef __attribute__((ext_vector_type(4))) float f32x4;

__device__ __forceinline__ unsigned short f2b(float f) {
    unsigned u = __float_as_uint(f);
    return (unsigned short)((u + 0x7fffu + ((u >> 16) & 1u)) >> 16);
}
__device__ __forceinline__ float b2f(unsigned short v) {
    return __uint_as_float(((unsigned)v) << 16);
}
__device__ __forceinline__ void llds16(const unsigned short* g, unsigned short* s) {
    __builtin_amdgcn_global_load_lds(
        (const __attribute__((address_space(1))) void*)g,
        (__attribute__((address_space(3))) void*)s, 16, 0, 0);
}

// ------------------------------------------------- prep + rank (one dispatch)
// blocks [0,12500): x->bf16 cast, weight transpose/cast
// blocks [12500,15625): rank[e] = old count in XCD-local replica deg8[idx&7]
__global__ __launch_bounds__(256) void k_prep_rank(
        const float* __restrict__ x,
        const float* __restrict__ W1l, const float* __restrict__ W1r,
        const float* __restrict__ W2l, const float* __restrict__ W2r,
        ushortT* __restrict__ Ac, ushortT* __restrict__ WT1,
        ushortT* __restrict__ WT2,
        const int* __restrict__ dst, int* __restrict__ deg8,
        int* __restrict__ rank) {
    int bid = blockIdx.x;
    if (bid < 12500) {
        int t = bid * 256 + threadIdx.x;          // [0, NN*32)
        int row = t >> 5, c4 = t & 31;
        float4 v = *(const float4*)&x[(size_t)row * 128 + c4 * 4];
        ushortT* p = Ac + (size_t)row * 256 + 128 + c4 * 4;
        p[0] = f2b(v.x); p[1] = f2b(v.y); p[2] = f2b(v.z); p[3] = f2b(v.w);

        if (t < 65536) {                          // WT1 [256n][256k]
            int n = t >> 8, k = t & 255;
            float w = (k < 128) ? W1l[(size_t)k * 256 + n]
                                : W1r[(size_t)(k - 128) * 256 + n];
            WT1[t] = f2b(w);
        } else if (t < 65536 + 20480) {           // WT2 [80n][256k]
            int j = t - 65536;
            int n = j >> 8, k = j & 255;
            float w = (n < 40) ? W2l[(size_t)k * 40 + n]
                               : W2r[(size_t)k * 40 + (n - 40)];
            WT2[j] = f2b(w);
        }
    } else {
        int idx = bid - 12500;                    // [0,3125)
        int e = idx * 256 + threadIdx.x;          // 3125*256 == NE
        int r = idx & 7;                          // replica == XCD (heuristic)
        rank[e] = atomicAdd(&deg8[r * NN + dst[e]], 1);
    }
}

// ------------------------------------------- scan over summed replica degs
// rp[i] = block-local exclusive prefix of deg_tot; rpp[r][i] = rp[i] +
// sum of replicas < r (fill's per-replica base). bsum = per-block totals.
__global__ __launch_bounds__(256) void k_scan1(const int* __restrict__ deg8,
                                               int* __restrict__ rp,
                                               int* __restrict__ rpp,
                                               int* __restrict__ bsum) {
    __shared__ int s[256];
    int t = threadIdx.x;
    int i = blockIdx.x * 256 + t;
    int d8[8];
    int v = 0;
#pragma unroll
    for (int r = 0; r < 8; ++r) {
        d8[r] = (i < NN) ? deg8[r * NN + i] : 0;
        v += d8[r];
    }
    s[t] = v;
    __syncthreads();
    for (int off = 1; off < 256; off <<= 1) {
        int add = (t >= off) ? s[t - off] : 0;
        __syncthreads();
        s[t] += add;
        __syncthreads();
    }
    int ex = s[t] - v;
    if (i <= NN) rp[i] = ex;                      // i==NN: v=0 -> exclusive end
    if (i < NN) {
        int run = ex;
#pragma unroll
        for (int r = 0; r < 8; ++r) {
            rpp[r * NN + i] = run;
            run += d8[r];
        }
    }
    if (t == 255) bsum[blockIdx.x] = s[255];
}

__global__ __launch_bounds__(512) void k_scan2(int* __restrict__ bsum) {
    __shared__ int s[512];
    int t = threadIdx.x;
    int v = (t < NB1) ? bsum[t] : 0;
    s[t] = v;
    __syncthreads();
    for (int off = 1; off < 512; off <<= 1) {
        int add = (t >= off) ? s[t - off] : 0;
        __syncthreads();
        s[t] += add;
        __syncthreads();
    }
    if (t < NB1) bsum[t] = s[t] - v;              // exclusive block offsets
}

// ------------------------------------------------- XCD-partitioned CSR fill
// 8 blocks share each 2048-edge chunk; block (fbid&7) writes only dsts in
// its 12500-node slice -> each col region written by one XCD (no line
// bouncing, dense writebacks). pos = bsum + rpp[replica][d] + rank[e].
__global__ __launch_bounds__(256) void k_fill(const int* __restrict__ src,
                                              const int* __restrict__ dst,
                                              const int* __restrict__ rank,
                                              const int* __restrict__ rpp,
                                              const int* __restrict__ bsum,
                                              int* __restrict__ col) {
    int fbid = blockIdx.x;
    int chunk = fbid >> 3;
    int lo = (fbid & 7) * 12500, hi = lo + 12500;
    int base = chunk * 2048 + threadIdx.x;
#pragma unroll
    for (int j = 0; j < 8; ++j) {
        int e = base + j * 256;
        if (e < NE) {
            int d = dst[e];
            if (d >= lo && d < hi) {
                int r = (e >> 8) & 7;
                col[bsum[d >> 8] + rpp[r * NN + d] + rank[e]] = src[e];
            }
        }
    }
}

// ------------------------------------------------------- mean aggregation 1
// gather bf16 x rows (A_cat[:,128:]), write bf16 mean to A_cat[:,0:128].
// One wave per node; col prefetch + __shfl bcast; 8 row-loads in flight.
__global__ __launch_bounds__(256) void k_agg1(const int* __restrict__ rp,
                                              const int* __restrict__ bsum,
                                              const int* __restrict__ col,
                                              ushortT* __restrict__ Ac) {
    int node = blockIdx.x * 4 + (threadIdx.x >> 6);
    int l = threadIdx.x & 63;
    if (node >= NN) return;
    int seg = l >> 4, dl = l & 15;
    int beg = rp[node] + bsum[node >> 8];
    int end = rp[node + 1] + bsum[(node + 1) >> 8];
    int deg = end - beg;
    float a[8] = {0.f, 0.f, 0.f, 0.f, 0.f, 0.f, 0.f, 0.f};
    for (int base = 0; base < deg; base += 64) {
        int cnt = min(64, deg - base);
        int cv = col[beg + base + min(l, cnt - 1)];
        for (int j = 0; j < cnt; j += 8) {
            int e0 = j + seg, e1 = j + 4 + seg;
            int i0 = __shfl(cv, min(e0, cnt - 1));
            int i1 = __shfl(cv, min(e1, cnt - 1));
            bf16x8 v0 = {0, 0, 0, 0, 0, 0, 0, 0};
            bf16x8 v1 = {0, 0, 0, 0, 0, 0, 0, 0};
            if (e0 < cnt) v0 = *(const bf16x8*)(Ac + (size_t)i0 * 256 + 128 + dl * 8);
            if (e1 < cnt) v1 = *(const bf16x8*)(Ac + (size_t)i1 * 256 + 128 + dl * 8);
#pragma unroll
            for (int i = 0; i < 8; ++i)
                a[i] += b2f((unsigned short)v0[i]) + b2f((unsigned short)v1[i]);
        }
    }
#pragma unroll
    for (int i = 0; i < 8; ++i) {
        a[i] += __shfl_xor(a[i], 16);
        a[i] += __shfl_xor(a[i], 32);
    }
    if (seg == 0) {
        float inv = 1.0f / fmaxf((float)deg, 1.0f);
        bf16x8 o;
#pragma unroll
        for (int i = 0; i < 8; ++i) o[i] = (short)f2b(a[i] * inv);
        *(bf16x8*)(Ac + (size_t)node * 256 + dl * 8) = o;
    }
}

// --------------------------------------------------------- fused L1+L2 GEMM
// Per 64-row block:  phase1: h64x256 = relu(Ac @ WT1^T + b1) -> LDS only.
//                    phase2: [y2|t] = h @ WT2^T (+b2), B-frags from L2.
// 4 waves side-by-side in N (wave 64x64, acc 4x4 = 64 AGPR). LDS 41 KB.
#define HSP 264   // h-tile LDS row stride (+8 pad)
__global__ __launch_bounds__(256, 3) void k_fused(
        const ushortT* __restrict__ Ac, const ushortT* __restrict__ WT1,
        const float* __restrict__ b1, const ushortT* __restrict__ WT2,
        const float* __restrict__ b2, ushortT* __restrict__ y2,
        ushortT* __restrict__ t) {
    __shared__ ushortT As[64 * 64];      // 8 KB
    __shared__ ushortT Bs[64 * HSP];     // 33 KB; phase1 B uses [0,16384)
    const int tid = threadIdx.x, l = tid & 63, wid = tid >> 6;
    const int m0 = blockIdx.x * 64;
    const int q = l >> 4, r = l & 15;
    const int swz = (l & 7) ^ ((l >> 3) & 7);

    f32x4 acc[4][4];
#pragma unroll
    for (int i = 0; i < 4; ++i)
#pragma unroll
        for (int j = 0; j < 4; ++j) acc[i][j] = (f32x4){0.f, 0.f, 0.f, 0.f};

    for (int kt = 0; kt < 256; kt += 64) {
#pragma unroll
        for (int i = 0; i < 2; ++i) {             // A: 8 issues of 1 KB
            int flat = wid * 2 + i;
            int row = flat * 8 + (l >> 3);
            llds16(Ac + (size_t)(m0 + row) * 256 + kt + swz * 8, &As[flat * 512]);
        }
#pragma unroll
        for (int i = 0; i < 8; ++i) {             // B: 32 issues of 1 KB
            int flat = wid * 8 + i;
            int row = flat * 8 + (l >> 3);
            llds16(WT1 + (size_t)row * 256 + kt + swz * 8, &Bs[flat * 512]);
        }
        __syncthreads();
#pragma unroll
        for (int ks = 0; ks < 64; ks += 32) {
            bf16x8 af[4], bfr[4];
            const int cs = (((ks >> 3) + q) ^ (r & 7)) * 8;
#pragma unroll
            for (int mt = 0; mt < 4; ++mt)
                af[mt] = *(const bf16x8*)&As[(mt * 16 + r) * 64 + cs];
#pragma unroll
            for (int nt = 0; nt < 4; ++nt)
                bfr[nt] = *(const bf16x8*)&Bs[(wid * 64 + nt * 16 + r) * 64 + cs];
#pragma unroll
            for (int mt = 0; mt < 4; ++mt)
#pragma unroll
                for (int nt = 0; nt < 4; ++nt)
                    acc[mt][nt] = __builtin_amdgcn_mfma_f32_16x16x32_bf16(
                        af[mt], bfr[nt], acc[mt][nt], 0, 0, 0);
        }
        __syncthreads();
    }
    // phase-1 epilogue: +b1, relu, park h-tile in LDS (overwrite Bs)
#pragma unroll
    for (int nt = 0; nt < 4; ++nt) {
        int colb = wid * 64 + nt * 16 + r;
        float bb = b1[colb];
#pragma unroll
        for (int mt = 0; mt < 4; ++mt) {
            int rowb = mt * 16 + q * 4;
#pragma unroll
            for (int j = 0; j < 4; ++j)
                Bs[(rowb + j) * HSP + colb] = f2b(fmaxf(acc[mt][nt][j] + bb, 0.f));
        }
    }
    __syncthreads();

    // phase 2: [y2|t](64x80) = h(LDS) @ WT2^T; wave wid covers col-tiles
    // {wid, wid+4 if <5}; A-frags from LDS, B-frags straight from L2.
    f32x4 acc2[2][4];
#pragma unroll
    for (int i = 0; i < 2; ++i)
#pragma unroll
        for (int j = 0; j < 4; ++j) acc2[i][j] = (f32x4){0.f, 0.f, 0.f, 0.f};
#pragma unroll
    for (int kk = 0; kk < 256; kk += 32) {
        bf16x8 af[4];
#pragma unroll
        for (int mt = 0; mt < 4; ++mt)
            af[mt] = *(const bf16x8*)&Bs[(mt * 16 + r) * HSP + kk + q * 8];
#pragma unroll
        for (int cc = 0; cc < 2; ++cc) {
            int ct = wid + cc * 4;
            if (ct < 5) {
                bf16x8 bq = *(const bf16x8*)(WT2 + (size_t)(ct * 16 + r) * 256 + kk + q * 8);
#pragma unroll
                for (int mt = 0; mt < 4; ++mt)
                    acc2[cc][mt] = __builtin_amdgcn_mfma_f32_16x16x32_bf16(
                        af[mt], bq, acc2[cc][mt], 0, 0, 0);
            }
        }
    }
#pragma unroll
    for (int cc = 0; cc < 2; ++cc) {
        int ct = wid + cc * 4;
        if (ct >= 5) continue;
        int c = ct * 16 + r;
        float bb = (c >= 40) ? b2[c - 40] : 0.f;
#pragma unroll
        for (int mt = 0; mt < 4; ++mt) {
            int row0 = m0 + mt * 16 + q * 4;
#pragma unroll
            for (int j = 0; j < 4; ++j) {
                float v = acc2[cc][mt][j];
                if (c < 40)
                    y2[(size_t)(row0 + j) * 40 + c] = f2b(v);
                else
                    t[(size_t)(row0 + j) * 40 + (c - 40)] = f2b(v + bb);
            }
        }
    }
}

// ------------------------------------------------------- mean aggregation 2
// out = mean_gather(y2 bf16) + t(bf16); col prefetch + 8 loads in flight.
__global__ __launch_bounds__(256) void k_agg2(const int* __restrict__ rp,
                                              const int* __restrict__ bsum,
                                              const int* __restrict__ col,
                                              const ushortT* __restrict__ y2,
                                              const ushortT* __restrict__ t,
                                              float* __restrict__ out) {
    int node = blockIdx.x * 4 + (threadIdx.x >> 6);
    int l = threadIdx.x & 63;
    if (node >= NN) return;
    int seg = l >> 4, dl = l & 15;
    int beg = rp[node] + bsum[node >> 8];
    int end = rp[node + 1] + bsum[(node + 1) >> 8];
    int deg = end - beg;
    bool act = dl < 10;
    float a0 = 0.f, a1 = 0.f, a2 = 0.f, a3 = 0.f;
    for (int base = 0; base < deg; base += 64) {
        int cnt = min(64, deg - base);
        int cv = col[beg + base + min(l, cnt - 1)];
        for (int j = 0; j < cnt; j += 8) {
            int e0 = j + seg, e1 = j + 4 + seg;
            int i0 = __shfl(cv, min(e0, cnt - 1));
            int i1 = __shfl(cv, min(e1, cnt - 1));
            ushort4 v0 = {0, 0, 0, 0}, v1 = {0, 0, 0, 0};
            if (e0 < cnt && act) v0 = *(const ushort4*)(y2 + (size_t)i0 * 40 + dl * 4);
            if (e1 < cnt && act) v1 = *(const ushort4*)(y2 + (size_t)i1 * 40 + dl * 4);
            a0 += b2f(v0.x) + b2f(v1.x);
            a1 += b2f(v0.y) + b2f(v1.y);
            a2 += b2f(v0.z) + b2f(v1.z);
            a3 += b2f(v0.w) + b2f(v1.w);
        }
    }
    a0 += __shfl_xor(a0, 16); a0 += __shfl_xor(a0, 32);
    a1 += __shfl_xor(a1, 16); a1 += __shfl_xor(a1, 32);
    a2 += __shfl_xor(a2, 16); a2 += __shfl_xor(a2, 32);
    a3 += __shfl_xor(a3, 16); a3 += __shfl_xor(a3, 32);
    if (seg == 0 && act) {
        float inv = 1.0f / fmaxf((float)deg, 1.0f);
        size_t o = (size_t)node * 40 + dl * 4;
        ushort4 tv = *(const ushort4*)&t[o];
        float4 ov;
        ov.x = a0 * inv + b2f(tv.x);
        ov.y = a1 * inv + b2f(tv.y);
        ov.z = a2 * inv + b2f(tv.z);
        ov.w = a3 * inv + b2f(tv.w);
        *(float4*)&out[o] = ov;
    }
}

// ------------------------------------------------------------------- launch
extern "C" void kernel_launch(void* const* d_in, const int* in_sizes, int n_in,
                              void* d_out, int out_size, void* d_ws, size_t ws_size,
                              hipStream_t stream) {
    const float* x   = (const float*)d_in[0];
    const int*   ei  = (const int*)d_in[1];
    const int*   src = ei;
    const int*   dst = ei + NE;
    const float* W1l = (const float*)d_in[2];
    const float* b1  = (const float*)d_in[3];
    const float* W1r = (const float*)d_in[4];
    const float* W2l = (const float*)d_in[5];
    const float* b2  = (const float*)d_in[6];
    const float* W2r = (const float*)d_in[7];
    float* out = (float*)d_out;

    size_t off = 0;
    char* base = (char*)d_ws;
    auto alloc = [&](size_t bytes) -> void* {
        void* p = base + off;
        off += (bytes + 255) & ~(size_t)255;
        return p;
    };
    int*     deg8  = (int*)alloc((size_t)8 * NN * 4);
    int*     rp    = (int*)alloc((size_t)(NN + 1) * 4);
    int*     rpp   = (int*)alloc((size_t)8 * NN * 4);
    int*     rank  = (int*)alloc((size_t)NE * 4);
    int*     col   = (int*)alloc((size_t)NE * 4);
    int*     bsum  = (int*)alloc(512 * 4);
    ushortT* Ac    = (ushortT*)alloc((size_t)NNP * 256 * 2);   // [agg|x] bf16
    ushortT* y2    = (ushortT*)alloc((size_t)NNP * 40 * 2);
    ushortT* t     = (ushortT*)alloc((size_t)NNP * 40 * 2);
    ushortT* WT1   = (ushortT*)alloc(256 * 256 * 2);
    ushortT* WT2   = (ushortT*)alloc(80 * 256 * 2);

    hipMemsetAsync(deg8, 0, (size_t)8 * NN * 4, stream);
    k_prep_rank<<<15625, 256, 0, stream>>>(x, W1l, W1r, W2l, W2r, Ac, WT1, WT2,
                                           dst, deg8, rank);
    k_scan1<<<NB1, 256, 0, stream>>>(deg8, rp, rpp, bsum);
    k_scan2<<<1, 512, 0, stream>>>(bsum);
    k_fill<<<391 * 8, 256, 0, stream>>>(src, dst, rank, rpp, bsum, col);
    k_agg1<<<(NN + 3) / 4, 256, 0, stream>>>(rp, bsum, col, Ac);
    k_fused<<<NNP / 64, 256, 0, stream>>>(Ac, WT1, b1, WT2, b2, y2, t);
    k_agg2<<<(NN + 3) / 4, 256, 0, stream>>>(rp, bsum, col, y2, t, out);
}